// Round 10
// baseline (5520.420 us; speedup 1.0000x reference)
//
#include <hip/hip_runtime.h>
#include <math.h>

#define BB 256
#define TT 128
#define DD 128
#define HH 1024
#define G4 4096
#define TOUT 127
#define OSZ (BB * TOUT * DD)
#define NKB 36                  // (128+1024)/32 K-blocks of the gates GEMM
#define ACTE (16 * NKB * 512)   // u16 elems of one activation frag-blob: 294912

typedef __bf16 bf16x8 __attribute__((ext_vector_type(8)));
typedef float f32x4 __attribute__((ext_vector_type(4)));
typedef unsigned short u16;
typedef unsigned int u32;
typedef unsigned long long u64;

#define MFMA16 __builtin_amdgcn_mfma_f32_16x16x32_bf16

__device__ inline u16 f2bf(float f) {
    union { float f; u32 u; } v; v.f = f;
    u32 r = v.u + 0x7FFFu + ((v.u >> 16) & 1u);
    return (u16)(r >> 16);
}
__device__ inline float fsig(float x)  { return __fdividef(1.0f, 1.0f + __expf(-x)); }
__device__ inline float ftanh(float x) { return __fdividef(2.0f, 1.0f + __expf(-2.0f * x)) - 1.0f; }

// Coherent (agent-scope, relaxed) access: bypasses stale L1/L2, served at the
// L3 coherence point. NO cache-maintenance fences anywhere in this kernel.
__device__ __forceinline__ u64 ldc64(const u64* p) {
    return __hip_atomic_load(p, __ATOMIC_RELAXED, __HIP_MEMORY_SCOPE_AGENT);
}
__device__ __forceinline__ bf16x8 ldc128(const u16* p) {
    union { u64 q[2]; bf16x8 v; } u;
    u.q[0] = ldc64((const u64*)p);
    u.q[1] = ldc64((const u64*)p + 1);
    return u.v;
}
__device__ __forceinline__ void stc32(u16* p, u32 v) {
    __hip_atomic_store((u32*)p, v, __ATOMIC_RELAXED, __HIP_MEMORY_SCOPE_AGENT);
}
__device__ __forceinline__ void stcf(float* p, float v) {
    __hip_atomic_store(p, v, __ATOMIC_RELAXED, __HIP_MEMORY_SCOPE_AGENT);
}
__device__ __forceinline__ float ldcf(const float* p) {
    return __hip_atomic_load(p, __ATOMIC_RELAXED, __HIP_MEMORY_SCOPE_AGENT);
}

struct SArgs {
    u16 *acts, *actp;                       // single frag-blobs (hs+inp / hp+xin)
    const u16 *wS, *wP, *fswb, *pfcb;       // frag-ordered weight blobs (L2-resident)
    const float *bS, *bP, *fsb, *pfb, *x;
    float *mbuf, *out;
    u32 *bars, *epoch, *flags;
};

// Hierarchical epoch barrier: 32 padded counters (8 arrivals each); block 0
// polls counters then publishes one epoch word; everyone polls epoch only.
__device__ __forceinline__ void gbar(u32* bars, u32* epoch, u32 gen) {
    asm volatile("s_waitcnt vmcnt(0)" ::: "memory");
    __syncthreads();
    if (threadIdx.x == 0)
        __hip_atomic_fetch_add(&bars[(blockIdx.x & 31) << 4], 1u,
                               __ATOMIC_RELAXED, __HIP_MEMORY_SCOPE_AGENT);
    if (blockIdx.x == 0 && threadIdx.x < 32) {
        while (__hip_atomic_load(&bars[threadIdx.x << 4],
                                 __ATOMIC_RELAXED, __HIP_MEMORY_SCOPE_AGENT) < gen * 8u)
            __builtin_amdgcn_s_sleep(1);
        if (threadIdx.x == 0)
            __hip_atomic_store(epoch, gen, __ATOMIC_RELAXED, __HIP_MEMORY_SCOPE_AGENT);
    }
    if (threadIdx.x == 0) {
        while (__hip_atomic_load(epoch, __ATOMIC_RELAXED, __HIP_MEMORY_SCOPE_AGENT) < gen)
            __builtin_amdgcn_s_sleep(1);
    }
    __syncthreads();
}

// x-part (4 K-blocks, direct coherent loads) + fused LSTM cell epilogue.
__device__ __forceinline__ void gates_tail(
    const SArgs& A, f32x4 acc0, f32x4 acc1,
    const u16* xpart, const u16* wb, const float* bias,
    float* cm, u16* hout, int bm, int bn, int w, int lane)
{
#pragma unroll
    for (int kb = 0; kb < 4; ++kb) {
        bf16x8 a0 = ldc128(xpart + (size_t)kb * 512 + lane * 8);
        bf16x8 a1 = ldc128(xpart + (size_t)(36 + kb) * 512 + lane * 8);
        bf16x8 bv = *(const bf16x8*)(wb + ((size_t)(bn * 8 + w) * 36 + kb) * 512 + lane * 8);
        acc0 = MFMA16(a0, bv, acc0, 0, 0, 0);
        acc1 = MFMA16(a1, bv, acc1, 0, 0, 0);
    }
    const int col = lane & 15, row4 = (lane >> 4) << 2, g0 = lane & 3;
    const int n = bn * 128 + w * 16 + col;
    const int j = n >> 2;
    const float bvv = bias[n];
    const int jl = w * 4 + (col >> 2);
#pragma unroll
    for (int mi = 0; mi < 2; ++mi) {
        f32x4 av = mi ? acc1 : acc0;
#pragma unroll
        for (int rr = 0; rr < 4; ++rr) {
            float v = av[rr] + bvv;
            float v1 = __shfl_xor(v, 1), v2 = __shfl_xor(v, 2), v3 = __shfl_xor(v, 3);
            const int m = bm * 32 + mi * 16 + row4 + rr;
            u32 hb = 0;
            if (g0 == 0) {  // lane holds gate i; v1=f, v2=g, v3=o
                const int ml = mi * 16 + row4 + rr;
                float cp = cm[ml * 32 + jl];
                float cy = cp * fsig(v1) + fsig(v) * ftanh(v2);
                float hy = fsig(v3) * ftanh(cy);
                cm[ml * 32 + jl] = cy;
                hb = (u32)f2bf(hy);
            }
            u32 pv = hb | (((u32)__shfl_xor((int)hb, 4)) << 16);
            if ((lane & 7) == 0)
                stc32(&hout[((size_t)(m >> 4) * 36 + (4 + (j >> 5))) * 512 +
                            ((m & 15) + (((j >> 3) & 3) << 4)) * 8 + (j & 7)], pv);
        }
    }
}

// One fused phase: gates GEMM h-part (32 iters, reading prestaged LDS panel,
// B register-direct from L2) with (a) next-phase h-panel prestage interleaved
// in 4 chunks, (b) M- or F-task interleaved 1:1 on designated blocks, then
// flag-wait -> x-part tail -> cell epilogue. TASK: 1 = M(mu), 2 = F(fc).
template<int TASK>
__device__ __forceinline__ void gphase(
    const SArgs& A, int t, int bid, int tid, int w, int lane,
    const u64* a_rd, u64* a_wr, const u64* pre_src,
    const u16* xpart, const u16* wb, const float* bias,
    float* cm, u16* hout)
{
    const int bm = bid >> 5, bn = bid & 31;
    const bool dotask = (TASK == 1) ? (bid < 16) : (bid < 32);
    const int tau = bid * 8 + w;

    const u16 *tA = nullptr, *tB = nullptr;
    if (dotask) {
        if (TASK == 1) {
            const int mg = tau >> 3, dg = tau & 7;
            tA = A.acts + ((size_t)mg * 36 + 4) * 512 + lane * 8;
            tB = A.fswb + (size_t)(dg * 32) * 512 + lane * 8;
        } else {
            const int mg = tau >> 4, ng = tau & 15;
            tA = A.actp + ((size_t)mg * 36 + 4) * 512 + lane * 8;
            tB = A.pfcb + (size_t)(ng * 32) * 512 + lane * 8;
        }
    }

    f32x4 acc0 = {}, acc1 = {}, tacc = {};
    const bf16x8* Ard = (const bf16x8*)a_rd;
    const u16* bp = wb + ((size_t)(bn * 8 + w) * 36 + 4) * 512 + lane * 8;
    bf16x8 bcur = *(const bf16x8*)bp;

#pragma unroll 1
    for (int g = 0; g < 4; ++g) {
        u64 pr0, pr1, pr2, pr3;
        {
            const int pb = g * 2048 + tid;
            int p;
            p = pb;        pr0 = ldc64(pre_src + ((p >> 12) * 4608 + 512 + (p & 4095)));
            p = pb + 512;  pr1 = ldc64(pre_src + ((p >> 12) * 4608 + 512 + (p & 4095)));
            p = pb + 1024; pr2 = ldc64(pre_src + ((p >> 12) * 4608 + 512 + (p & 4095)));
            p = pb + 1536; pr3 = ldc64(pre_src + ((p >> 12) * 4608 + 512 + (p & 4095)));
        }
#pragma unroll
        for (int i = 0; i < 8; ++i) {
            const int it = g * 8 + i;
            bf16x8 bnx = *(const bf16x8*)(bp + (size_t)((it < 31) ? (it + 1) : it) * 512);
            bf16x8 a0 = Ard[(size_t)it * 64 + lane];
            bf16x8 a1 = Ard[(size_t)(32 + it) * 64 + lane];
            acc0 = MFMA16(a0, bcur, acc0, 0, 0, 0);
            acc1 = MFMA16(a1, bcur, acc1, 0, 0, 0);
            if (dotask) {
                bf16x8 tav = ldc128(tA + (size_t)it * 512);
                bf16x8 tbv = *(const bf16x8*)(tB + (size_t)it * 512);
                tacc = MFMA16(tav, tbv, tacc, 0, 0, 0);
            }
            bcur = bnx;
        }
        {
            const int pb = g * 2048 + tid;
            a_wr[pb] = pr0; a_wr[pb + 512] = pr1;
            a_wr[pb + 1024] = pr2; a_wr[pb + 1536] = pr3;
        }
    }

    // ---- task epilogue + flag publish ----
    if (dotask) {
        const int col = lane & 15, row4 = (lane >> 4) << 2;
        if (TASK == 1) {  // mu -> mask/reg/mu/prob/z outputs, mbuf, xin blob
            const int mg = tau >> 3, dg = tau & 7;
            const int d = dg * 16 + col;
            const float bv = A.fsb[d];
#pragma unroll
            for (int rr = 0; rr < 4; ++rr) {
                const int m = mg * 16 + row4 + rr;
                float mu = tacc[rr] + bv;
                float mask = fminf(fmaxf(mu + 0.5f, 0.f), 1.f);
                float reg = 0.5f * (1.f + erff((mu + 0.5f) * 1.41421356237f));
                const size_t o = (size_t)m * (TOUT * DD) + (size_t)t * DD + d;
                A.out[o] = mask;
                A.out[o + 3 * (size_t)OSZ] = reg;
                A.out[o + 4 * (size_t)OSZ] = mu;
                A.out[o + 5 * (size_t)OSZ] = reg;
                A.out[o + 6 * (size_t)OSZ] = mu;
                stcf(&A.mbuf[m * DD + d], mask);
                float xv = A.x[(size_t)m * (TT * DD) + (size_t)(t + 1) * DD + d];
                u32 xb = (u32)f2bf(mask * xv);
                u32 pv = xb | (((u32)__shfl_xor((int)xb, 1)) << 16);
                if ((lane & 1) == 0)
                    stc32(&A.actp[((size_t)(m >> 4) * 36 + (d >> 5)) * 512 +
                                  ((m & 15) + (((d >> 3) & 3) << 4)) * 8 + (d & 7)], pv);
            }
        } else {  // fc -> xhat0/xhat1 outputs, inp blob
            const int mg = tau >> 4, ng = tau & 15;
            const int n = ng * 16 + col;
            const float bv = A.pfb[n];
#pragma unroll
            for (int rr = 0; rr < 4; ++rr) {
                const int m = mg * 16 + row4 + rr;
                float v = tacc[rr] + bv;
                const size_t ob = (size_t)m * (TOUT * DD) + (size_t)t * DD;
                if (ng < 8) {
                    A.out[ob + n + (size_t)OSZ] = v;
                    float mk = ldcf(&A.mbuf[m * DD + n]);
                    float xv = A.x[(size_t)m * (TT * DD) + (size_t)(t + 1) * DD + n];
                    u32 ib = (u32)f2bf(mk * xv + (1.f - mk) * v);
                    u32 pv = ib | (((u32)__shfl_xor((int)ib, 1)) << 16);
                    if ((lane & 1) == 0)
                        stc32(&A.acts[((size_t)(m >> 4) * 36 + (n >> 5)) * 512 +
                                      ((m & 15) + (((n >> 3) & 3) << 4)) * 8 + (n & 7)], pv);
                } else {
                    A.out[ob + (n - DD) + 2 * (size_t)OSZ] = v;
                }
            }
        }
        asm volatile("s_waitcnt vmcnt(0)" ::: "memory");
        if (lane == 0) {
            const int f = (TASK == 1) ? tau : (128 + tau);
            __hip_atomic_store(&A.flags[f << 4], (u32)(t + 1),
                               __ATOMIC_RELAXED, __HIP_MEMORY_SCOPE_AGENT);
        }
    }

    // ---- wait for my 16 x-part producer flags (wave0 polls, block syncs) ----
    if (w == 0 && lane < 16) {
        const int f = (TASK == 1) ? (16 * bm + lane)
                                  : (128 + 32 * bm + (lane & 7) + ((lane >> 3) << 4));
        const u32 need = (u32)(t + 1);
        while (__hip_atomic_load(&A.flags[f << 4],
                                 __ATOMIC_RELAXED, __HIP_MEMORY_SCOPE_AGENT) < need)
            __builtin_amdgcn_s_sleep(1);
    }
    __syncthreads();

    gates_tail(A, acc0, acc1, xpart, wb, bias, cm, hout, bm, bn, w, lane);
}

__global__ __launch_bounds__(512, 1) void k_scan(SArgs A)
{
    __shared__ __align__(16) u64 aS[8192];      // 64 KB: hs-panel (kblk 4..35)
    __shared__ __align__(16) u64 aP[8192];      // 64 KB: hp-panel
    __shared__ float cst[2][32][32];            // 8 KB persistent c state (s,p)

    const int bid = blockIdx.x, tid = threadIdx.x;
    const int w = tid >> 6, lane = tid & 63;
    const int bm = bid >> 5;

    for (int i = tid; i < 2 * 32 * 32; i += 512) ((float*)cst)[i] = 0.f;
    for (int i = tid; i < 8192; i += 512) aP[i] = 0;  // hp(-1) = 0
    __syncthreads();

    u32 gen = 0;

    // ---- phase0: S(0) = LSTM(inp0, 0): x-part only (h-part is zero) ----
    {
        f32x4 z0 = {}, z1 = {};
        gates_tail(A, z0, z1, A.acts + (size_t)(2 * bm) * 36 * 512, A.wS, A.bS,
                   &cst[0][0][0], A.acts, bm, bid & 31, w, lane);
        gbar(A.bars, A.epoch, ++gen);
    }

    for (int t = 0; t < TOUT; ++t) {
        // ---- Phase1: M-tasks || gates-P (+ prestage aS <- hs(t)) ----
        gphase<1>(A, t, bid, tid, w, lane, aP, aS,
                  (const u64*)A.acts + (size_t)(2 * bm) * 4608,
                  A.actp + (size_t)(2 * bm) * 36 * 512,
                  A.wP, A.bP, &cst[1][0][0], A.actp);
        gbar(A.bars, A.epoch, ++gen);

        if (t < TOUT - 1) {
            // ---- Phase2: F-tasks || gates-S(t+1) (+ prestage aP <- hp(t)) ----
            gphase<2>(A, t, bid, tid, w, lane, aS, aP,
                      (const u64*)A.actp + (size_t)(2 * bm) * 4608,
                      A.acts + (size_t)(2 * bm) * 36 * 512,
                      A.wS, A.bS, &cst[0][0][0], A.acts);
            gbar(A.bars, A.epoch, ++gen);
        } else {
            // ---- final step: F outputs only (no S(127) needed) ----
            if (bid < 32) {
                const int tau = bid * 8 + w;
                const int mg = tau >> 4, ng = tau & 15;
                const u16* tA = A.actp + ((size_t)mg * 36 + 4) * 512 + lane * 8;
                const u16* tB = A.pfcb + (size_t)(ng * 32) * 512 + lane * 8;
                f32x4 tacc = {};
#pragma unroll 8
                for (int it = 0; it < 32; ++it) {
                    bf16x8 tav = ldc128(tA + (size_t)it * 512);
                    bf16x8 tbv = *(const bf16x8*)(tB + (size_t)it * 512);
                    tacc = MFMA16(tav, tbv, tacc, 0, 0, 0);
                }
                const int col = lane & 15, row4 = (lane >> 4) << 2;
                const int n = ng * 16 + col;
                const float bv = A.pfb[n];
#pragma unroll
                for (int rr = 0; rr < 4; ++rr) {
                    const int m = mg * 16 + row4 + rr;
                    float v = tacc[rr] + bv;
                    const size_t ob = (size_t)m * (TOUT * DD) + (size_t)t * DD;
                    if (ng < 8) A.out[ob + n + (size_t)OSZ] = v;
                    else        A.out[ob + (n - DD) + 2 * (size_t)OSZ] = v;
                }
            }
        }
    }
}

// ---------------- setup kernels (once per call) ----------------

__global__ void k_wgates(const float* __restrict__ wx, const float* __restrict__ wh,
                         u16* __restrict__ blob) {
    int i = blockIdx.x * 256 + threadIdx.x;
    if (i >= 256 * NKB * 64) return;
    int lane = i & 63, cblk = (i >> 6) % NKB, rblk = (i >> 6) / NKB;
    int n = (rblk << 4) | (lane & 15);
    int c = (cblk << 5) + ((lane >> 4) << 3);
    int orow = ((n & 3) << 10) | (n >> 2);
    const float* s = (cblk < 4) ? (wx + (size_t)orow * DD + c)
                                : (wh + (size_t)orow * HH + (c - 128));
    u16* d = blob + (size_t)i * 8;
#pragma unroll
    for (int k = 0; k < 8; ++k) d[k] = f2bf(s[k]);
}

__global__ void k_wplain(const float* __restrict__ wsrc, u16* __restrict__ blob,
                         int nblk, int K) {
    int CB = K >> 5;
    int i = blockIdx.x * 256 + threadIdx.x;
    if (i >= nblk * CB * 64) return;
    int lane = i & 63, cblk = (i >> 6) % CB, rblk = (i >> 6) / CB;
    int r = (rblk << 4) | (lane & 15);
    int c = (cblk << 5) + ((lane >> 4) << 3);
    const float* s = wsrc + (size_t)r * K + c;
    u16* d = blob + (size_t)i * 8;
#pragma unroll
    for (int k = 0; k < 8; ++k) d[k] = f2bf(s[k]);
}

__global__ void k_bias2(const float* __restrict__ bx, const float* __restrict__ bh,
                        float* __restrict__ dst) {
    int r = blockIdx.x * 256 + threadIdx.x;
    if (r < G4) {
        int o = ((r & 3) << 10) | (r >> 2);
        dst[r] = bx[o] + bh[o];
    }
}

__global__ void k_zero(u16* acts, u16* actp, float* mbuf,
                       u32* bars, u32* epoch, u32* flags) {
    size_t i = (size_t)blockIdx.x * 256 + threadIdx.x;
    if (i < (size_t)ACTE) { acts[i] = 0; actp[i] = 0; }
    if (i < (size_t)BB * DD) mbuf[i] = 0.f;
    if (i < 512) bars[i] = 0;
    if (i < 16) epoch[i] = 0;
    if (i < 6144) flags[i] = 0;
}

__global__ void k_fillx(const float* __restrict__ x, u16* __restrict__ acts) {
    int i = blockIdx.x * 256 + threadIdx.x;
    if (i >= BB * DD) return;
    int m = i >> 7, d = i & 127;
    acts[(((size_t)(m >> 4) * NKB + (d >> 5)) * 64 +
          ((m & 15) + (((d >> 3) & 3) << 4))) * 8 + (d & 7)] =
        f2bf(x[(size_t)m * (TT * DD) + d]);
}

extern "C" void kernel_launch(void* const* d_in, const int* in_sizes, int n_in,
                              void* d_out, int out_size, void* d_ws, size_t ws_size,
                              hipStream_t stream) {
    const float* x       = (const float*)d_in[0];
    const float* s_x2h_w = (const float*)d_in[1];
    const float* s_x2h_b = (const float*)d_in[2];
    const float* s_h2h_w = (const float*)d_in[3];
    const float* s_h2h_b = (const float*)d_in[4];
    const float* p_x2h_w = (const float*)d_in[5];
    const float* p_x2h_b = (const float*)d_in[6];
    const float* p_h2h_w = (const float*)d_in[7];
    const float* p_h2h_b = (const float*)d_in[8];
    const float* p_fc_w  = (const float*)d_in[9];
    const float* p_fc_b  = (const float*)d_in[10];
    const float* fs_w    = (const float*)d_in[11];
    const float* fs_b    = (const float*)d_in[12];

    char* ws = (char*)d_ws;
    size_t off = 0;
    auto alloc = [&](size_t bytes) { void* p = ws + off; off += (bytes + 255) & ~(size_t)255; return p; };
    u16*   wS    = (u16*)  alloc((size_t)G4 * 1152 * 2);
    u16*   wP    = (u16*)  alloc((size_t)G4 * 1152 * 2);
    u16*   fswb  = (u16*)  alloc((size_t)8 * 32 * 512 * 2);
    u16*   pfcb  = (u16*)  alloc((size_t)16 * 32 * 512 * 2);
    float* bS    = (float*)alloc((size_t)G4 * 4);
    float* bP    = (float*)alloc((size_t)G4 * 4);
    u16*   acts  = (u16*)  alloc((size_t)ACTE * 2);
    u16*   actp  = (u16*)  alloc((size_t)ACTE * 2);
    float* mbuf  = (float*)alloc((size_t)BB * DD * 4);
    u32*   bars  = (u32*)  alloc(512 * 4);
    u32*   epoch = (u32*)  alloc(16 * 4);
    u32*   flags = (u32*)  alloc(6144 * 4);

    k_wgates<<<dim3(2304), 256, 0, stream>>>(s_x2h_w, s_h2h_w, wS);
    k_wgates<<<dim3(2304), 256, 0, stream>>>(p_x2h_w, p_h2h_w, wP);
    k_wplain<<<dim3(64),  256, 0, stream>>>(fs_w, fswb, 8, 1024);
    k_wplain<<<dim3(128), 256, 0, stream>>>(p_fc_w, pfcb, 16, 1024);
    k_bias2<<<dim3(16), 256, 0, stream>>>(s_x2h_b, s_h2h_b, bS);
    k_bias2<<<dim3(16), 256, 0, stream>>>(p_x2h_b, p_h2h_b, bP);
    k_zero<<<dim3(1152), 256, 0, stream>>>(acts, actp, mbuf, bars, epoch, flags);
    k_fillx<<<dim3(128), 256, 0, stream>>>(x, acts);

    SArgs sa;
    sa.acts = acts; sa.actp = actp;
    sa.wS = wS; sa.wP = wP; sa.fswb = fswb; sa.pfcb = pfcb;
    sa.bS = bS; sa.bP = bP; sa.fsb = fs_b; sa.pfb = p_fc_b; sa.x = x;
    sa.mbuf = mbuf; sa.out = (float*)d_out;
    sa.bars = bars; sa.epoch = epoch; sa.flags = flags;

    void* kargs[] = { &sa };
    hipError_t e = hipLaunchCooperativeKernel((const void*)k_scan, dim3(256), dim3(512),
                                              kargs, 0, stream);
    if (e != hipSuccess) {
        k_scan<<<dim3(256), dim3(512), 0, stream>>>(sa);
    }
}

// Round 11
// 5429.642 us; speedup vs baseline: 1.0167x; 1.0167x over previous
//
#include <hip/hip_runtime.h>
#include <math.h>

#define BB 256
#define TT 128
#define DD 128
#define HH 1024
#define G4 4096
#define TOUT 127
#define OSZ (BB * TOUT * DD)
#define NKB 36                  // (128+1024)/32 K-blocks of the gates GEMM
#define ACTE (16 * NKB * 512)   // u16 elems of one activation frag-blob: 294912

typedef __bf16 bf16x8 __attribute__((ext_vector_type(8)));
typedef float f32x4 __attribute__((ext_vector_type(4)));
typedef unsigned short u16;
typedef unsigned int u32;
typedef unsigned long long u64;

#define MFMA16 __builtin_amdgcn_mfma_f32_16x16x32_bf16

__device__ inline u16 f2bf(float f) {
    union { float f; u32 u; } v; v.f = f;
    u32 r = v.u + 0x7FFFu + ((v.u >> 16) & 1u);
    return (u16)(r >> 16);
}
__device__ inline float fsig(float x)  { return __fdividef(1.0f, 1.0f + __expf(-x)); }
__device__ inline float ftanh(float x) { return __fdividef(2.0f, 1.0f + __expf(-2.0f * x)) - 1.0f; }

// Coherent (agent-scope, relaxed) access: bypasses stale L1/L2, served at the
// L3 coherence point. NO cache-maintenance fences anywhere in this kernel.
__device__ __forceinline__ u64 ldc64(const u64* p) {
    return __hip_atomic_load(p, __ATOMIC_RELAXED, __HIP_MEMORY_SCOPE_AGENT);
}
__device__ __forceinline__ bf16x8 ldc128(const u16* p) {
    union { u64 q[2]; bf16x8 v; } u;
    u.q[0] = ldc64((const u64*)p);
    u.q[1] = ldc64((const u64*)p + 1);
    return u.v;
}
__device__ __forceinline__ void stc32(u16* p, u32 v) {
    __hip_atomic_store((u32*)p, v, __ATOMIC_RELAXED, __HIP_MEMORY_SCOPE_AGENT);
}
__device__ __forceinline__ void stcf(float* p, float v) {
    __hip_atomic_store(p, v, __ATOMIC_RELAXED, __HIP_MEMORY_SCOPE_AGENT);
}
__device__ __forceinline__ float ldcf(const float* p) {
    return __hip_atomic_load(p, __ATOMIC_RELAXED, __HIP_MEMORY_SCOPE_AGENT);
}

struct SArgs {
    u16 *acts, *actp;                       // single frag-blobs (hs+inp / hp+xin)
    const u16 *wS, *wP, *fswb, *pfcb;       // frag-ordered weight blobs (L2-resident)
    const float *bS, *bP, *fsb, *pfb, *x;
    float *mbuf, *out;
    u32 *bars, *epoch, *flags;
};

// Hierarchical epoch barrier: 32 padded counters (8 arrivals each); block 0
// polls counters then publishes one epoch word; everyone polls epoch only.
__device__ __forceinline__ void gbar(u32* bars, u32* epoch, u32 gen) {
    asm volatile("s_waitcnt vmcnt(0)" ::: "memory");
    __syncthreads();
    if (threadIdx.x == 0)
        __hip_atomic_fetch_add(&bars[(blockIdx.x & 31) << 4], 1u,
                               __ATOMIC_RELAXED, __HIP_MEMORY_SCOPE_AGENT);
    if (blockIdx.x == 0 && threadIdx.x < 32) {
        while (__hip_atomic_load(&bars[threadIdx.x << 4],
                                 __ATOMIC_RELAXED, __HIP_MEMORY_SCOPE_AGENT) < gen * 8u)
            __builtin_amdgcn_s_sleep(1);
        if (threadIdx.x == 0)
            __hip_atomic_store(epoch, gen, __ATOMIC_RELAXED, __HIP_MEMORY_SCOPE_AGENT);
    }
    if (threadIdx.x == 0) {
        while (__hip_atomic_load(epoch, __ATOMIC_RELAXED, __HIP_MEMORY_SCOPE_AGENT) < gen)
            __builtin_amdgcn_s_sleep(1);
    }
    __syncthreads();
}

// x-part (4 K-blocks, direct coherent loads) + fused LSTM cell epilogue.
__device__ __forceinline__ void gates_tail(
    const SArgs& A, f32x4 acc0, f32x4 acc1,
    const u16* xpart, const u16* wb, const float* bias,
    float* cm, u16* hout, int bm, int bn, int w, int lane)
{
#pragma unroll
    for (int kb = 0; kb < 4; ++kb) {
        bf16x8 a0 = ldc128(xpart + (size_t)kb * 512 + lane * 8);
        bf16x8 a1 = ldc128(xpart + (size_t)(36 + kb) * 512 + lane * 8);
        bf16x8 bv = *(const bf16x8*)(wb + ((size_t)(bn * 8 + w) * 36 + kb) * 512 + lane * 8);
        acc0 = MFMA16(a0, bv, acc0, 0, 0, 0);
        acc1 = MFMA16(a1, bv, acc1, 0, 0, 0);
    }
    const int col = lane & 15, row4 = (lane >> 4) << 2, g0 = lane & 3;
    const int n = bn * 128 + w * 16 + col;
    const int j = n >> 2;
    const float bvv = bias[n];
    const int jl = w * 4 + (col >> 2);
#pragma unroll
    for (int mi = 0; mi < 2; ++mi) {
        f32x4 av = mi ? acc1 : acc0;
#pragma unroll
        for (int rr = 0; rr < 4; ++rr) {
            float v = av[rr] + bvv;
            float v1 = __shfl_xor(v, 1), v2 = __shfl_xor(v, 2), v3 = __shfl_xor(v, 3);
            const int m = bm * 32 + mi * 16 + row4 + rr;
            u32 hb = 0;
            if (g0 == 0) {  // lane holds gate i; v1=f, v2=g, v3=o
                const int ml = mi * 16 + row4 + rr;
                float cp = cm[ml * 32 + jl];
                float cy = cp * fsig(v1) + fsig(v) * ftanh(v2);
                float hy = fsig(v3) * ftanh(cy);
                cm[ml * 32 + jl] = cy;
                hb = (u32)f2bf(hy);
            }
            u32 pv = hb | (((u32)__shfl_xor((int)hb, 4)) << 16);
            if ((lane & 7) == 0)
                stc32(&hout[((size_t)(m >> 4) * 36 + (4 + (j >> 5))) * 512 +
                            ((m & 15) + (((j >> 3) & 3) << 4)) * 8 + (j & 7)], pv);
        }
    }
}

// One fused phase: gates GEMM h-part (32 iters, reading prestaged LDS panel,
// B register-direct from L2) with (a) next-phase h-panel prestage interleaved
// in 4 chunks, (b) M- or F-task interleaved 1:1 on designated blocks, then
// flag-wait -> x-part tail -> cell epilogue. TASK: 1 = M(mu), 2 = F(fc).
template<int TASK>
__device__ __forceinline__ void gphase(
    const SArgs& A, int t, int bid, int tid, int w, int lane,
    const u64* a_rd, u64* a_wr, const u64* pre_src,
    const u16* xpart, const u16* wb, const float* bias,
    float* cm, u16* hout)
{
    const int bm = bid >> 5, bn = bid & 31;
    const bool dotask = (TASK == 1) ? (bid < 16) : (bid < 32);
    const int tau = bid * 8 + w;

    const u16 *tA = nullptr, *tB = nullptr;
    if (dotask) {
        if (TASK == 1) {
            const int mg = tau >> 3, dg = tau & 7;
            tA = A.acts + ((size_t)mg * 36 + 4) * 512 + lane * 8;
            tB = A.fswb + (size_t)(dg * 32) * 512 + lane * 8;
        } else {
            const int mg = tau >> 4, ng = tau & 15;
            tA = A.actp + ((size_t)mg * 36 + 4) * 512 + lane * 8;
            tB = A.pfcb + (size_t)(ng * 32) * 512 + lane * 8;
        }
    }

    f32x4 acc0 = {}, acc1 = {}, tacc = {};
    const bf16x8* Ard = (const bf16x8*)a_rd;
    const u16* bp = wb + ((size_t)(bn * 8 + w) * 36 + 4) * 512 + lane * 8;
    bf16x8 bcur = *(const bf16x8*)bp;

#pragma unroll 1
    for (int g = 0; g < 4; ++g) {
        u64 pr0, pr1, pr2, pr3;
        {
            const int pb = g * 2048 + tid;
            int p;
            p = pb;        pr0 = ldc64(pre_src + ((p >> 12) * 4608 + 512 + (p & 4095)));
            p = pb + 512;  pr1 = ldc64(pre_src + ((p >> 12) * 4608 + 512 + (p & 4095)));
            p = pb + 1024; pr2 = ldc64(pre_src + ((p >> 12) * 4608 + 512 + (p & 4095)));
            p = pb + 1536; pr3 = ldc64(pre_src + ((p >> 12) * 4608 + 512 + (p & 4095)));
        }
#pragma unroll
        for (int i = 0; i < 8; ++i) {
            const int it = g * 8 + i;
            bf16x8 bnx = *(const bf16x8*)(bp + (size_t)((it < 31) ? (it + 1) : it) * 512);
            bf16x8 a0 = Ard[(size_t)it * 64 + lane];
            bf16x8 a1 = Ard[(size_t)(32 + it) * 64 + lane];
            acc0 = MFMA16(a0, bcur, acc0, 0, 0, 0);
            acc1 = MFMA16(a1, bcur, acc1, 0, 0, 0);
            if (dotask) {
                bf16x8 tav = ldc128(tA + (size_t)it * 512);
                bf16x8 tbv = *(const bf16x8*)(tB + (size_t)it * 512);
                tacc = MFMA16(tav, tbv, tacc, 0, 0, 0);
            }
            bcur = bnx;
        }
        {
            const int pb = g * 2048 + tid;
            a_wr[pb] = pr0; a_wr[pb + 512] = pr1;
            a_wr[pb + 1024] = pr2; a_wr[pb + 1536] = pr3;
        }
    }

    // ---- task epilogue + flag publish ----
    if (dotask) {
        const int col = lane & 15, row4 = (lane >> 4) << 2;
        if (TASK == 1) {  // mu -> mask/reg/mu/prob/z outputs, mbuf, xin blob
            const int mg = tau >> 3, dg = tau & 7;
            const int d = dg * 16 + col;
            const float bv = A.fsb[d];
#pragma unroll
            for (int rr = 0; rr < 4; ++rr) {
                const int m = mg * 16 + row4 + rr;
                float mu = tacc[rr] + bv;
                float mask = fminf(fmaxf(mu + 0.5f, 0.f), 1.f);
                float reg = 0.5f * (1.f + erff((mu + 0.5f) * 1.41421356237f));
                const size_t o = (size_t)m * (TOUT * DD) + (size_t)t * DD + d;
                A.out[o] = mask;
                A.out[o + 3 * (size_t)OSZ] = reg;
                A.out[o + 4 * (size_t)OSZ] = mu;
                A.out[o + 5 * (size_t)OSZ] = reg;
                A.out[o + 6 * (size_t)OSZ] = mu;
                stcf(&A.mbuf[m * DD + d], mask);
                float xv = A.x[(size_t)m * (TT * DD) + (size_t)(t + 1) * DD + d];
                u32 xb = (u32)f2bf(mask * xv);
                u32 pv = xb | (((u32)__shfl_xor((int)xb, 1)) << 16);
                if ((lane & 1) == 0)
                    stc32(&A.actp[((size_t)(m >> 4) * 36 + (d >> 5)) * 512 +
                                  ((m & 15) + (((d >> 3) & 3) << 4)) * 8 + (d & 7)], pv);
            }
        } else {  // fc -> xhat0/xhat1 outputs, inp blob
            const int mg = tau >> 4, ng = tau & 15;
            const int n = ng * 16 + col;
            const float bv = A.pfb[n];
#pragma unroll
            for (int rr = 0; rr < 4; ++rr) {
                const int m = mg * 16 + row4 + rr;
                float v = tacc[rr] + bv;
                const size_t ob = (size_t)m * (TOUT * DD) + (size_t)t * DD;
                if (ng < 8) {
                    A.out[ob + n + (size_t)OSZ] = v;
                    float mk = ldcf(&A.mbuf[m * DD + n]);
                    float xv = A.x[(size_t)m * (TT * DD) + (size_t)(t + 1) * DD + n];
                    u32 ib = (u32)f2bf(mk * xv + (1.f - mk) * v);
                    u32 pv = ib | (((u32)__shfl_xor((int)ib, 1)) << 16);
                    if ((lane & 1) == 0)
                        stc32(&A.acts[((size_t)(m >> 4) * 36 + (n >> 5)) * 512 +
                                      ((m & 15) + (((n >> 3) & 3) << 4)) * 8 + (n & 7)], pv);
                } else {
                    A.out[ob + (n - DD) + 2 * (size_t)OSZ] = v;
                }
            }
        }
        asm volatile("s_waitcnt vmcnt(0)" ::: "memory");
        if (lane == 0) {
            const int f = (TASK == 1) ? tau : (128 + tau);
            __hip_atomic_store(&A.flags[f << 4], (u32)(t + 1),
                               __ATOMIC_RELAXED, __HIP_MEMORY_SCOPE_AGENT);
        }
    }

    // ---- wait for my 16 x-part producer flags (wave0 polls, block syncs) ----
    if (w == 0 && lane < 16) {
        const int f = (TASK == 1) ? (16 * bm + lane)
                                  : (128 + 32 * bm + (lane & 7) + ((lane >> 3) << 4));
        const u32 need = (u32)(t + 1);
        while (__hip_atomic_load(&A.flags[f << 4],
                                 __ATOMIC_RELAXED, __HIP_MEMORY_SCOPE_AGENT) < need)
            __builtin_amdgcn_s_sleep(1);
    }
    __syncthreads();

    gates_tail(A, acc0, acc1, xpart, wb, bias, cm, hout, bm, bn, w, lane);
}

__global__ __launch_bounds__(512, 1) void k_scan(SArgs A)
{
    __shared__ __align__(16) u64 aS[8192];      // 64 KB: hs-panel (kblk 4..35)
    __shared__ __align__(16) u64 aP[8192];      // 64 KB: hp-panel
    __shared__ float cst[2][32][32];            // 8 KB persistent c state (s,p)

    const int bid = blockIdx.x, tid = threadIdx.x;
    const int w = tid >> 6, lane = tid & 63;
    const int bm = bid >> 5;

    for (int i = tid; i < 2 * 32 * 32; i += 512) ((float*)cst)[i] = 0.f;
    for (int i = tid; i < 8192; i += 512) aP[i] = 0;  // hp(-1) = 0
    __syncthreads();

    u32 gen = 0;

    // ---- phase0: S(0) = LSTM(inp0, 0): x-part only (h-part is zero) ----
    {
        f32x4 z0 = {}, z1 = {};
        gates_tail(A, z0, z1, A.acts + (size_t)(2 * bm) * 36 * 512, A.wS, A.bS,
                   &cst[0][0][0], A.acts, bm, bid & 31, w, lane);
        gbar(A.bars, A.epoch, ++gen);
    }

    for (int t = 0; t < TOUT; ++t) {
        // ---- Phase1: M-tasks || gates-P (+ prestage aS <- hs(t)) ----
        gphase<1>(A, t, bid, tid, w, lane, aP, aS,
                  (const u64*)A.acts + (size_t)(2 * bm) * 4608,
                  A.actp + (size_t)(2 * bm) * 36 * 512,
                  A.wP, A.bP, &cst[1][0][0], A.actp);
        gbar(A.bars, A.epoch, ++gen);

        if (t < TOUT - 1) {
            // ---- Phase2: F-tasks || gates-S(t+1) (+ prestage aP <- hp(t)) ----
            gphase<2>(A, t, bid, tid, w, lane, aS, aP,
                      (const u64*)A.actp + (size_t)(2 * bm) * 4608,
                      A.acts + (size_t)(2 * bm) * 36 * 512,
                      A.wS, A.bS, &cst[0][0][0], A.acts);
            gbar(A.bars, A.epoch, ++gen);
        } else {
            // ---- final step: F outputs only (no S(127) needed) ----
            if (bid < 32) {
                const int tau = bid * 8 + w;
                const int mg = tau >> 4, ng = tau & 15;
                const u16* tA = A.actp + ((size_t)mg * 36 + 4) * 512 + lane * 8;
                const u16* tB = A.pfcb + (size_t)(ng * 32) * 512 + lane * 8;
                f32x4 tacc = {};
#pragma unroll 8
                for (int it = 0; it < 32; ++it) {
                    bf16x8 tav = ldc128(tA + (size_t)it * 512);
                    bf16x8 tbv = *(const bf16x8*)(tB + (size_t)it * 512);
                    tacc = MFMA16(tav, tbv, tacc, 0, 0, 0);
                }
                const int col = lane & 15, row4 = (lane >> 4) << 2;
                const int n = ng * 16 + col;
                const float bv = A.pfb[n];
#pragma unroll
                for (int rr = 0; rr < 4; ++rr) {
                    const int m = mg * 16 + row4 + rr;
                    float v = tacc[rr] + bv;
                    const size_t ob = (size_t)m * (TOUT * DD) + (size_t)t * DD;
                    if (ng < 8) A.out[ob + n + (size_t)OSZ] = v;
                    else        A.out[ob + (n - DD) + 2 * (size_t)OSZ] = v;
                }
            }
        }
    }
}

// ---------------- setup kernels (once per call) ----------------

__global__ void k_wgates(const float* __restrict__ wx, const float* __restrict__ wh,
                         u16* __restrict__ blob) {
    int i = blockIdx.x * 256 + threadIdx.x;
    if (i >= 256 * NKB * 64) return;
    int lane = i & 63, cblk = (i >> 6) % NKB, rblk = (i >> 6) / NKB;
    int n = (rblk << 4) | (lane & 15);
    int c = (cblk << 5) + ((lane >> 4) << 3);
    int orow = ((n & 3) << 10) | (n >> 2);
    const float* s = (cblk < 4) ? (wx + (size_t)orow * DD + c)
                                : (wh + (size_t)orow * HH + (c - 128));
    u16* d = blob + (size_t)i * 8;
#pragma unroll
    for (int k = 0; k < 8; ++k) d[k] = f2bf(s[k]);
}

__global__ void k_wplain(const float* __restrict__ wsrc, u16* __restrict__ blob,
                         int nblk, int K) {
    int CB = K >> 5;
    int i = blockIdx.x * 256 + threadIdx.x;
    if (i >= nblk * CB * 64) return;
    int lane = i & 63, cblk = (i >> 6) % CB, rblk = (i >> 6) / CB;
    int r = (rblk << 4) | (lane & 15);
    int c = (cblk << 5) + ((lane >> 4) << 3);
    const float* s = wsrc + (size_t)r * K + c;
    u16* d = blob + (size_t)i * 8;
#pragma unroll
    for (int k = 0; k < 8; ++k) d[k] = f2bf(s[k]);
}

__global__ void k_bias2(const float* __restrict__ bx, const float* __restrict__ bh,
                        float* __restrict__ dst) {
    int r = blockIdx.x * 256 + threadIdx.x;
    if (r < G4) {
        int o = ((r & 3) << 10) | (r >> 2);
        dst[r] = bx[o] + bh[o];
    }
}

__global__ void k_zero(u16* acts, u16* actp, float* mbuf,
                       u32* bars, u32* epoch, u32* flags) {
    size_t i = (size_t)blockIdx.x * 256 + threadIdx.x;
    if (i < (size_t)ACTE) { acts[i] = 0; actp[i] = 0; }
    if (i < (size_t)BB * DD) mbuf[i] = 0.f;
    if (i < 512) bars[i] = 0;
    if (i < 16) epoch[i] = 0;
    if (i < 6144) flags[i] = 0;
}

__global__ void k_fillx(const float* __restrict__ x, u16* __restrict__ acts) {
    int i = blockIdx.x * 256 + threadIdx.x;
    if (i >= BB * DD) return;
    int m = i >> 7, d = i & 127;
    acts[(((size_t)(m >> 4) * NKB + (d >> 5)) * 64 +
          ((m & 15) + (((d >> 3) & 3) << 4))) * 8 + (d & 7)] =
        f2bf(x[(size_t)m * (TT * DD) + d]);
}

extern "C" void kernel_launch(void* const* d_in, const int* in_sizes, int n_in,
                              void* d_out, int out_size, void* d_ws, size_t ws_size,
                              hipStream_t stream) {
    const float* x       = (const float*)d_in[0];
    const float* s_x2h_w = (const float*)d_in[1];
    const float* s_x2h_b = (const float*)d_in[2];
    const float* s_h2h_w = (const float*)d_in[3];
    const float* s_h2h_b = (const float*)d_in[4];
    const float* p_x2h_w = (const float*)d_in[5];
    const float* p_x2h_b = (const float*)d_in[6];
    const float* p_h2h_w = (const float*)d_in[7];
    const float* p_h2h_b = (const float*)d_in[8];
    const float* p_fc_w  = (const float*)d_in[9];
    const float* p_fc_b  = (const float*)d_in[10];
    const float* fs_w    = (const float*)d_in[11];
    const float* fs_b    = (const float*)d_in[12];

    char* ws = (char*)d_ws;
    size_t off = 0;
    auto alloc = [&](size_t bytes) { void* p = ws + off; off += (bytes + 255) & ~(size_t)255; return p; };
    u16*   wS    = (u16*)  alloc((size_t)G4 * 1152 * 2);
    u16*   wP    = (u16*)  alloc((size_t)G4 * 1152 * 2);
    u16*   fswb  = (u16*)  alloc((size_t)8 * 32 * 512 * 2);
    u16*   pfcb  = (u16*)  alloc((size_t)16 * 32 * 512 * 2);
    float* bS    = (float*)alloc((size_t)G4 * 4);
    float* bP    = (float*)alloc((size_t)G4 * 4);
    u16*   acts  = (u16*)  alloc((size_t)ACTE * 2);
    u16*   actp  = (u16*)  alloc((size_t)ACTE * 2);
    float* mbuf  = (float*)alloc((size_t)BB * DD * 4);
    u32*   bars  = (u32*)  alloc(512 * 4);
    u32*   epoch = (u32*)  alloc(16 * 4);
    u32*   flags = (u32*)  alloc(6144 * 4);

    k_wgates<<<dim3(2304), 256, 0, stream>>>(s_x2h_w, s_h2h_w, wS);
    k_wgates<<<dim3(2304), 256, 0, stream>>>(p_x2h_w, p_h2h_w, wP);
    k_wplain<<<dim3(64),  256, 0, stream>>>(fs_w, fswb, 8, 1024);
    k_wplain<<<dim3(128), 256, 0, stream>>>(p_fc_w, pfcb, 16, 1024);
    k_bias2<<<dim3(16), 256, 0, stream>>>(s_x2h_b, s_h2h_b, bS);
    k_bias2<<<dim3(16), 256, 0, stream>>>(p_x2h_b, p_h2h_b, bP);
    k_zero<<<dim3(1152), 256, 0, stream>>>(acts, actp, mbuf, bars, epoch, flags);
    k_fillx<<<dim3(128), 256, 0, stream>>>(x, acts);

    SArgs sa;
    sa.acts = acts; sa.actp = actp;
    sa.wS = wS; sa.wP = wP; sa.fswb = fswb; sa.pfcb = pfcb;
    sa.bS = bS; sa.bP = bP; sa.fsb = fs_b; sa.pfb = p_fc_b; sa.x = x;
    sa.mbuf = mbuf; sa.out = (float*)d_out;
    sa.bars = bars; sa.epoch = epoch; sa.flags = flags;

    void* kargs[] = { &sa };
    hipError_t e = hipLaunchCooperativeKernel((const void*)k_scan, dim3(256), dim3(512),
                                              kargs, 0, stream);
    if (e != hipSuccess) {
        k_scan<<<dim3(256), dim3(512), 0, stream>>>(sa);
    }
}

// Round 12
// 5144.265 us; speedup vs baseline: 1.0731x; 1.0555x over previous
//
#include <hip/hip_runtime.h>
#include <math.h>

#define BB 256
#define TT 128
#define DD 128
#define HH 1024
#define G4 4096
#define TOUT 127
#define OSZ (BB * TOUT * DD)
#define NKB 36                  // (128+1024)/32 K-blocks of the gates GEMM
#define ACTE (16 * NKB * 512)   // u16 elems of one activation frag-blob: 294912

typedef __bf16 bf16x8 __attribute__((ext_vector_type(8)));
typedef float f32x4 __attribute__((ext_vector_type(4)));
typedef unsigned short u16;
typedef unsigned int u32;
typedef unsigned long long u64;

#define MFMA16 __builtin_amdgcn_mfma_f32_16x16x32_bf16

__device__ inline u16 f2bf(float f) {
    union { float f; u32 u; } v; v.f = f;
    u32 r = v.u + 0x7FFFu + ((v.u >> 16) & 1u);
    return (u16)(r >> 16);
}
__device__ inline float fsig(float x)  { return __fdividef(1.0f, 1.0f + __expf(-x)); }
__device__ inline float ftanh(float x) { return __fdividef(2.0f, 1.0f + __expf(-2.0f * x)) - 1.0f; }

// Coherent (agent-scope, relaxed) access: bypasses stale L1/L2, served at the
// coherence point. NO cache-maintenance fences anywhere in this kernel.
__device__ __forceinline__ u64 ldc64(const u64* p) {
    return __hip_atomic_load(p, __ATOMIC_RELAXED, __HIP_MEMORY_SCOPE_AGENT);
}
__device__ __forceinline__ bf16x8 ldc128(const u16* p) {
    union { u64 q[2]; bf16x8 v; } u;
    u.q[0] = ldc64((const u64*)p);
    u.q[1] = ldc64((const u64*)p + 1);
    return u.v;
}
__device__ __forceinline__ void stc32(u16* p, u32 v) {
    __hip_atomic_store((u32*)p, v, __ATOMIC_RELAXED, __HIP_MEMORY_SCOPE_AGENT);
}
__device__ __forceinline__ void stcf(float* p, float v) {
    __hip_atomic_store(p, v, __ATOMIC_RELAXED, __HIP_MEMORY_SCOPE_AGENT);
}
__device__ __forceinline__ float ldcf(const float* p) {
    return __hip_atomic_load(p, __ATOMIC_RELAXED, __HIP_MEMORY_SCOPE_AGENT);
}
__device__ __forceinline__ void fpoll(const u32* f, int idx, u32 need) {
    while (__hip_atomic_load(&f[idx << 4], __ATOMIC_RELAXED, __HIP_MEMORY_SCOPE_AGENT) < need)
        __builtin_amdgcn_s_sleep(1);
}
__device__ __forceinline__ void fpub(u32* f, int idx, u32 v) {
    __hip_atomic_store(&f[idx << 4], v, __ATOMIC_RELAXED, __HIP_MEMORY_SCOPE_AGENT);
}

struct SArgs {
    u16 *acts0, *acts1, *actp0, *actp1;     // parity-double-buffered frag blobs
    const u16 *wS, *wP, *fswb, *pfcb;       // frag-ordered weight blobs (L2-resident)
    const float *bS, *bP, *fsb, *pfb, *x;
    float *mbuf, *out;
    u32 *fS, *fP, *fM, *fF;                 // per-producer epoch flags (64B padded)
};

// x-part (4 K-blocks, coherent loads) + fused LSTM cell epilogue + h-blob write.
__device__ __forceinline__ void gates_tail(
    f32x4 acc0, f32x4 acc1,
    const u16* xpart, const u16* wb, const float* bias,
    float* cm, u16* hout, int bm, int bn, int w, int lane)
{
#pragma unroll
    for (int kb = 0; kb < 4; ++kb) {
        bf16x8 a0 = ldc128(xpart + (size_t)kb * 512 + lane * 8);
        bf16x8 a1 = ldc128(xpart + (size_t)(36 + kb) * 512 + lane * 8);
        bf16x8 bv = *(const bf16x8*)(wb + ((size_t)(bn * 8 + w) * 36 + kb) * 512 + lane * 8);
        acc0 = MFMA16(a0, bv, acc0, 0, 0, 0);
        acc1 = MFMA16(a1, bv, acc1, 0, 0, 0);
    }
    const int col = lane & 15, row4 = (lane >> 4) << 2, g0 = lane & 3;
    const int n = bn * 128 + w * 16 + col;
    const int j = n >> 2;
    const float bvv = bias[n];
    const int jl = w * 4 + (col >> 2);
#pragma unroll
    for (int mi = 0; mi < 2; ++mi) {
        f32x4 av = mi ? acc1 : acc0;
#pragma unroll
        for (int rr = 0; rr < 4; ++rr) {
            float v = av[rr] + bvv;
            float v1 = __shfl_xor(v, 1), v2 = __shfl_xor(v, 2), v3 = __shfl_xor(v, 3);
            const int m = bm * 32 + mi * 16 + row4 + rr;
            u32 hb = 0;
            if (g0 == 0) {  // lane holds gate i; v1=f, v2=g, v3=o
                const int ml = mi * 16 + row4 + rr;
                float cp = cm[ml * 32 + jl];
                float cy = cp * fsig(v1) + fsig(v) * ftanh(v2);
                float hy = fsig(v3) * ftanh(cy);
                cm[ml * 32 + jl] = cy;
                hb = (u32)f2bf(hy);
            }
            u32 pv = hb | (((u32)__shfl_xor((int)hb, 4)) << 16);
            if ((lane & 7) == 0)
                stc32(&hout[((size_t)(m >> 4) * 36 + (4 + (j >> 5))) * 512 +
                            ((m & 15) + (((j >> 3) & 3) << 4)) * 8 + (j & 7)], pv);
        }
    }
}

// One phase: gates h-part (32 iters from LDS panel, B from L2, prestage of the
// next panel interleaved) + one task wave (M: TASK=1, blocks bn<16; F: TASK=2,
// all blocks) + task epilogue/flag + x-tail flag-wait + gates_tail.
template<int TASK>
__device__ __forceinline__ void gphase(
    const SArgs& A, int t, int bid, int tid, int w, int lane,
    const u64* a_rd, u64* a_wr, const u64* pre_src,
    const u16* tAbase, u16* xinDst,
    const u16* xpart, const u16* wb, const float* bias,
    float* cm, u16* hout)
{
    const int bm = bid >> 5, bn = bid & 31;
    const bool dotask = (TASK == 1) ? (w == 7 && bn < 16) : (w == 7);
    const int tau = (TASK == 1) ? (bm * 16 + bn) : (bm * 32 + bn);

    const u16 *tA = nullptr, *tB = nullptr;
    if (dotask) {
        if (TASK == 1) {
            const int mg = tau >> 3, dg = tau & 7;
            tA = tAbase + ((size_t)mg * 36 + 4) * 512 + lane * 8;
            tB = A.fswb + (size_t)(dg * 32) * 512 + lane * 8;
        } else {
            const int mg = tau >> 4, ng = tau & 15;
            tA = tAbase + ((size_t)mg * 36 + 4) * 512 + lane * 8;
            tB = A.pfcb + (size_t)(ng * 32) * 512 + lane * 8;
        }
    }

    f32x4 acc0 = {}, acc1 = {}, tacc = {};
    const bf16x8* Ard = (const bf16x8*)a_rd;
    const u16* bp = wb + ((size_t)(bn * 8 + w) * 36 + 4) * 512 + lane * 8;
    bf16x8 bcur = *(const bf16x8*)bp;

#pragma unroll 1
    for (int g = 0; g < 4; ++g) {
        u64 pr0, pr1, pr2, pr3;
        {
            const int pb = g * 2048 + tid;
            int p;
            p = pb;        pr0 = ldc64(pre_src + ((p >> 12) * 4608 + 512 + (p & 4095)));
            p = pb + 512;  pr1 = ldc64(pre_src + ((p >> 12) * 4608 + 512 + (p & 4095)));
            p = pb + 1024; pr2 = ldc64(pre_src + ((p >> 12) * 4608 + 512 + (p & 4095)));
            p = pb + 1536; pr3 = ldc64(pre_src + ((p >> 12) * 4608 + 512 + (p & 4095)));
        }
#pragma unroll
        for (int i = 0; i < 8; ++i) {
            const int it = g * 8 + i;
            bf16x8 bnx = *(const bf16x8*)(bp + (size_t)((it < 31) ? (it + 1) : it) * 512);
            bf16x8 a0 = Ard[(size_t)it * 64 + lane];
            bf16x8 a1 = Ard[(size_t)(32 + it) * 64 + lane];
            acc0 = MFMA16(a0, bcur, acc0, 0, 0, 0);
            acc1 = MFMA16(a1, bcur, acc1, 0, 0, 0);
            if (dotask) {
                bf16x8 tav = ldc128(tA + (size_t)it * 512);
                bf16x8 tbv = *(const bf16x8*)(tB + (size_t)it * 512);
                tacc = MFMA16(tav, tbv, tacc, 0, 0, 0);
            }
            bcur = bnx;
        }
        {
            const int pb = g * 2048 + tid;
            a_wr[pb] = pr0; a_wr[pb + 512] = pr1;
            a_wr[pb + 1024] = pr2; a_wr[pb + 1536] = pr3;
        }
    }

    // ---- task epilogue + flag publish ----
    if (dotask) {
        const int col = lane & 15, row4 = (lane >> 4) << 2;
        if (TASK == 1) {  // mu -> mask/reg/mu/prob/z outputs, mbuf, xin blob
            const int mg = tau >> 3, dg = tau & 7;
            const int d = dg * 16 + col;
            const float bv = A.fsb[d];
#pragma unroll
            for (int rr = 0; rr < 4; ++rr) {
                const int m = mg * 16 + row4 + rr;
                float mu = tacc[rr] + bv;
                float mask = fminf(fmaxf(mu + 0.5f, 0.f), 1.f);
                float reg = 0.5f * (1.f + erff((mu + 0.5f) * 1.41421356237f));
                const size_t o = (size_t)m * (TOUT * DD) + (size_t)t * DD + d;
                A.out[o] = mask;
                A.out[o + 3 * (size_t)OSZ] = reg;
                A.out[o + 4 * (size_t)OSZ] = mu;
                A.out[o + 5 * (size_t)OSZ] = reg;
                A.out[o + 6 * (size_t)OSZ] = mu;
                stcf(&A.mbuf[m * DD + d], mask);
                float xv = A.x[(size_t)m * (TT * DD) + (size_t)(t + 1) * DD + d];
                u32 xb = (u32)f2bf(mask * xv);
                u32 pv = xb | (((u32)__shfl_xor((int)xb, 1)) << 16);
                if ((lane & 1) == 0)
                    stc32(&xinDst[((size_t)(m >> 4) * 36 + (d >> 5)) * 512 +
                                  ((m & 15) + (((d >> 3) & 3) << 4)) * 8 + (d & 7)], pv);
            }
        } else {  // fc -> xhat0/xhat1 outputs, inp blob
            const int mg = tau >> 4, ng = tau & 15;
            const int n = ng * 16 + col;
            const float bv = A.pfb[n];
#pragma unroll
            for (int rr = 0; rr < 4; ++rr) {
                const int m = mg * 16 + row4 + rr;
                float v = tacc[rr] + bv;
                const size_t ob = (size_t)m * (TOUT * DD) + (size_t)t * DD;
                if (ng < 8) {
                    A.out[ob + n + (size_t)OSZ] = v;
                    float mk = ldcf(&A.mbuf[m * DD + n]);
                    float xv = A.x[(size_t)m * (TT * DD) + (size_t)(t + 1) * DD + n];
                    u32 ib = (u32)f2bf(mk * xv + (1.f - mk) * v);
                    u32 pv = ib | (((u32)__shfl_xor((int)ib, 1)) << 16);
                    if ((lane & 1) == 0)
                        stc32(&xinDst[((size_t)(m >> 4) * 36 + (n >> 5)) * 512 +
                                      ((m & 15) + (((n >> 3) & 3) << 4)) * 8 + (n & 7)], pv);
                } else {
                    A.out[ob + (n - DD) + 2 * (size_t)OSZ] = v;
                }
            }
        }
        asm volatile("s_waitcnt vmcnt(0)" ::: "memory");
        if (lane == 0)
            fpub((TASK == 1) ? A.fM : A.fF, tau, (u32)(t + 1));
    }

    // ---- x-tail producer-flag wait (group-local, no global barrier) ----
    if (w == 0 && lane < 16) {
        if (TASK == 1) fpoll(A.fM, bm * 16 + lane, (u32)(t + 1));
        else           fpoll(A.fF, bm * 32 + (lane & 7) + ((lane >> 3) << 4), (u32)(t + 1));
    }
    __syncthreads();

    gates_tail(acc0, acc1, xpart, wb, bias, cm, hout, bm, bn, w, lane);
}

__global__ __launch_bounds__(512, 1) void k_scan(SArgs A)
{
    __shared__ __align__(16) u64 aS[8192];      // 64 KB: hs-panel (kblk 4..35)
    __shared__ __align__(16) u64 aP[8192];      // 64 KB: hp-panel
    __shared__ float cst[2][32][32];            // 8 KB persistent c state (s,p)

    const int bid = blockIdx.x, tid = threadIdx.x;
    const int w = tid >> 6, lane = tid & 63;
    const int bm = bid >> 5, bn = bid & 31;

    for (int i = tid; i < 2 * 32 * 32; i += 512) ((float*)cst)[i] = 0.f;
    for (int i = tid; i < 8192; i += 512) aP[i] = 0;  // hp(-1) = 0
    __syncthreads();

    // ---- phase0: S(0) = LSTM(inp0, 0): x-part only (h-part is zero) ----
    {
        f32x4 z0 = {}, z1 = {};
        gates_tail(z0, z1, A.acts0 + (size_t)(2 * bm) * 36 * 512, A.wS, A.bS,
                   &cst[0][0][0], A.acts0, bm, bn, w, lane);
        asm volatile("s_waitcnt vmcnt(0)" ::: "memory");
        __syncthreads();
        if (tid == 0) fpub(A.fS, bid, 1u);
    }

    for (int t = 0; t < TOUT; ++t) {
        const int par = t & 1;
        u16* hsb = par ? A.acts1 : A.acts0;   // hs(t) (+ inp(t)) blob
        u16* hpb = par ? A.actp1 : A.actp0;   // hp(t) (+ xin(t)) blob
        u16* nsb = par ? A.acts0 : A.acts1;   // hs(t+1) (+ inp(t+1)) blob

        // ---- Phase1: wait hs(t) ready (own bm group) ----
        if (w == 0 && lane < 32) fpoll(A.fS, bm * 32 + lane, (u32)(t + 1));
        __syncthreads();
        // gates-P(t): h-loop on aP(=hp(t-1)) + prestage aS<-hs(t) + M-task
        gphase<1>(A, t, bid, tid, w, lane, aP, aS,
                  (const u64*)hsb + (size_t)(2 * bm) * 4608,
                  hsb, hpb,
                  hpb + (size_t)(2 * bm) * 36 * 512,
                  A.wP, A.bP, &cst[1][0][0], hpb);
        asm volatile("s_waitcnt vmcnt(0)" ::: "memory");
        __syncthreads();
        if (tid == 0) fpub(A.fP, bid, (u32)(t + 1));

        // ---- Phase2: wait hp(t) ready (own bm group) ----
        if (w == 0 && lane < 32) fpoll(A.fP, bm * 32 + lane, (u32)(t + 1));
        __syncthreads();
        // gates-S(t+1): h-loop on aS(=hs(t)) + prestage aP<-hp(t) + F-task
        gphase<2>(A, t, bid, tid, w, lane, aS, aP,
                  (const u64*)hpb + (size_t)(2 * bm) * 4608,
                  hpb, nsb,
                  nsb + (size_t)(2 * bm) * 36 * 512,
                  A.wS, A.bS, &cst[0][0][0], nsb);
        asm volatile("s_waitcnt vmcnt(0)" ::: "memory");
        __syncthreads();
        if (tid == 0) fpub(A.fS, bid, (u32)(t + 2));
    }
}

// ---------------- setup kernels (once per call) ----------------

__global__ void k_wgates(const float* __restrict__ wx, const float* __restrict__ wh,
                         u16* __restrict__ blob) {
    int i = blockIdx.x * 256 + threadIdx.x;
    if (i >= 256 * NKB * 64) return;
    int lane = i & 63, cblk = (i >> 6) % NKB, rblk = (i >> 6) / NKB;
    int n = (rblk << 4) | (lane & 15);
    int c = (cblk << 5) + ((lane >> 4) << 3);
    int orow = ((n & 3) << 10) | (n >> 2);
    const float* s = (cblk < 4) ? (wx + (size_t)orow * DD + c)
                                : (wh + (size_t)orow * HH + (c - 128));
    u16* d = blob + (size_t)i * 8;
#pragma unroll
    for (int k = 0; k < 8; ++k) d[k] = f2bf(s[k]);
}

__global__ void k_wplain(const float* __restrict__ wsrc, u16* __restrict__ blob,
                         int nblk, int K) {
    int CB = K >> 5;
    int i = blockIdx.x * 256 + threadIdx.x;
    if (i >= nblk * CB * 64) return;
    int lane = i & 63, cblk = (i >> 6) % CB, rblk = (i >> 6) / CB;
    int r = (rblk << 4) | (lane & 15);
    int c = (cblk << 5) + ((lane >> 4) << 3);
    const float* s = wsrc + (size_t)r * K + c;
    u16* d = blob + (size_t)i * 8;
#pragma unroll
    for (int k = 0; k < 8; ++k) d[k] = f2bf(s[k]);
}

__global__ void k_bias2(const float* __restrict__ bx, const float* __restrict__ bh,
                        float* __restrict__ dst) {
    int r = blockIdx.x * 256 + threadIdx.x;
    if (r < G4) {
        int o = ((r & 3) << 10) | (r >> 2);
        dst[r] = bx[o] + bh[o];
    }
}

__global__ void k_zero(u16* acts, u16* actp, float* mbuf, u32* flags) {
    size_t i = (size_t)blockIdx.x * 256 + threadIdx.x;
    if (i < 2 * (size_t)ACTE) { acts[i] = 0; actp[i] = 0; }
    if (i < (size_t)BB * DD) mbuf[i] = 0.f;
    if (i < 14336) flags[i] = 0;
}

__global__ void k_fillx(const float* __restrict__ x, u16* __restrict__ acts) {
    int i = blockIdx.x * 256 + threadIdx.x;
    if (i >= BB * DD) return;
    int m = i >> 7, d = i & 127;
    acts[(((size_t)(m >> 4) * NKB + (d >> 5)) * 64 +
          ((m & 15) + (((d >> 3) & 3) << 4))) * 8 + (d & 7)] =
        f2bf(x[(size_t)m * (TT * DD) + d]);
}

extern "C" void kernel_launch(void* const* d_in, const int* in_sizes, int n_in,
                              void* d_out, int out_size, void* d_ws, size_t ws_size,
                              hipStream_t stream) {
    const float* x       = (const float*)d_in[0];
    const float* s_x2h_w = (const float*)d_in[1];
    const float* s_x2h_b = (const float*)d_in[2];
    const float* s_h2h_w = (const float*)d_in[3];
    const float* s_h2h_b = (const float*)d_in[4];
    const float* p_x2h_w = (const float*)d_in[5];
    const float* p_x2h_b = (const float*)d_in[6];
    const float* p_h2h_w = (const float*)d_in[7];
    const float* p_h2h_b = (const float*)d_in[8];
    const float* p_fc_w  = (const float*)d_in[9];
    const float* p_fc_b  = (const float*)d_in[10];
    const float* fs_w    = (const float*)d_in[11];
    const float* fs_b    = (const float*)d_in[12];

    char* ws = (char*)d_ws;
    size_t off = 0;
    auto alloc = [&](size_t bytes) { void* p = ws + off; off += (bytes + 255) & ~(size_t)255; return p; };
    u16*   wS    = (u16*)  alloc((size_t)G4 * 1152 * 2);
    u16*   wP    = (u16*)  alloc((size_t)G4 * 1152 * 2);
    u16*   fswb  = (u16*)  alloc((size_t)8 * 32 * 512 * 2);
    u16*   pfcb  = (u16*)  alloc((size_t)16 * 32 * 512 * 2);
    float* bS    = (float*)alloc((size_t)G4 * 4);
    float* bP    = (float*)alloc((size_t)G4 * 4);
    u16*   acts  = (u16*)  alloc((size_t)2 * ACTE * 2);  // parity 0/1
    u16*   actp  = (u16*)  alloc((size_t)2 * ACTE * 2);
    float* mbuf  = (float*)alloc((size_t)BB * DD * 4);
    u32*   flags = (u32*)  alloc(14336 * 4);             // fS,fP,fM,fF padded

    k_wgates<<<dim3(2304), 256, 0, stream>>>(s_x2h_w, s_h2h_w, wS);
    k_wgates<<<dim3(2304), 256, 0, stream>>>(p_x2h_w, p_h2h_w, wP);
    k_wplain<<<dim3(64),  256, 0, stream>>>(fs_w, fswb, 8, 1024);
    k_wplain<<<dim3(128), 256, 0, stream>>>(p_fc_w, pfcb, 16, 1024);
    k_bias2<<<dim3(16), 256, 0, stream>>>(s_x2h_b, s_h2h_b, bS);
    k_bias2<<<dim3(16), 256, 0, stream>>>(p_x2h_b, p_h2h_b, bP);
    k_zero<<<dim3(2304), 256, 0, stream>>>(acts, actp, mbuf, flags);
    k_fillx<<<dim3(128), 256, 0, stream>>>(x, acts);

    SArgs sa;
    sa.acts0 = acts; sa.acts1 = acts + ACTE;
    sa.actp0 = actp; sa.actp1 = actp + ACTE;
    sa.wS = wS; sa.wP = wP; sa.fswb = fswb; sa.pfcb = pfcb;
    sa.bS = bS; sa.bP = bP; sa.fsb = fs_b; sa.pfb = p_fc_b; sa.x = x;
    sa.mbuf = mbuf; sa.out = (float*)d_out;
    sa.fS = flags;            // 256 flags * 16
    sa.fP = flags + 4096;     // 256 * 16
    sa.fM = flags + 8192;     // 128 * 16
    sa.fF = flags + 10240;    // 256 * 16

    void* kargs[] = { &sa };
    hipError_t e = hipLaunchCooperativeKernel((const void*)k_scan, dim3(256), dim3(512),
                                              kargs, 0, stream);
    if (e != hipSuccess) {
        k_scan<<<dim3(256), dim3(512), 0, stream>>>(sa);
    }
}